// Round 1
// baseline (442.947 us; speedup 1.0000x reference)
//
#include <hip/hip_runtime.h>
#include <cstdint>
#include <cstddef>

typedef __attribute__((ext_vector_type(8))) short short8;
typedef __attribute__((ext_vector_type(4))) float f32x4;
typedef __attribute__((ext_vector_type(4))) uint16_t ushort4_t;

__device__ __forceinline__ uint16_t f2bf(float f) {
  union { float f; uint32_t u; } v; v.f = f;
  uint32_t r = v.u + 0x7FFFu + ((v.u >> 16) & 1u);
  return (uint16_t)(r >> 16);
}

// ---------------- conversion kernels ----------------

__global__ __launch_bounds__(256) void cvt_f32_bf16(const float* __restrict__ in,
                                                    uint16_t* __restrict__ out, int n4) {
  int i = blockIdx.x * 256 + threadIdx.x;
  int stride = gridDim.x * 256;
  for (; i < n4; i += stride) {
    float4 v = ((const float4*)in)[i];
    ushort4_t o = { f2bf(v.x), f2bf(v.y), f2bf(v.z), f2bf(v.w) };
    ((ushort4_t*)out)[i] = o;
  }
}

// out[C][R] (bf16) = transpose of in[R][C] (f32)
__global__ __launch_bounds__(256) void transpose_cvt(const float* __restrict__ in,
                                                     uint16_t* __restrict__ out, int R, int C) {
  __shared__ float tile[32][33];
  int c0 = blockIdx.x * 32, r0 = blockIdx.y * 32;
  int tx = threadIdx.x, ty = threadIdx.y;
#pragma unroll
  for (int j = 0; j < 32; j += 8)
    tile[ty + j][tx] = in[(size_t)(r0 + ty + j) * C + c0 + tx];
  __syncthreads();
#pragma unroll
  for (int j = 0; j < 32; j += 8)
    out[(size_t)(c0 + ty + j) * R + r0 + tx] = f2bf(tile[tx][ty + j]);
}

// v [BH][2048][64] bf16 -> vT [BH][64][2048] bf16
__global__ __launch_bounds__(256) void transpose_v(const uint16_t* __restrict__ in,
                                                   uint16_t* __restrict__ out) {
  __shared__ uint16_t tile[32][33];
  int bh = blockIdx.z;
  int t0 = blockIdx.x * 32, d0 = blockIdx.y * 32;
  const uint16_t* ip = in + (size_t)bh * 2048 * 64;
  uint16_t* op = out + (size_t)bh * 64 * 2048;
  int tx = threadIdx.x, ty = threadIdx.y;
#pragma unroll
  for (int j = 0; j < 32; j += 8)
    tile[ty + j][tx] = ip[(size_t)(t0 + ty + j) * 64 + d0 + tx];
  __syncthreads();
#pragma unroll
  for (int j = 0; j < 32; j += 8)
    op[(size_t)(d0 + ty + j) * 2048 + t0 + tx] = tile[tx][ty + j];
}

// ---------------- GEMM (128x128 tile, BK=64, 4 waves) ----------------

__device__ __forceinline__ void stage16(const uint16_t* g, uint16_t* lds) {
  __builtin_amdgcn_global_load_lds((__attribute__((address_space(1))) void*)g,
                                   (__attribute__((address_space(3))) void*)lds, 16, 0, 0);
}

// C[M][N] = A[M][K] * Bt[N][K]^T + bias
// MODE 0: scatter bf16 into q/k/v [B,H,T,D]; MODE 1: plain f32 row-major out
template <int MODE>
__global__ __launch_bounds__(256) void gemm128(
    const uint16_t* __restrict__ A, const uint16_t* __restrict__ Bt,
    const float* __restrict__ bias, int K,
    uint16_t* __restrict__ q_out, uint16_t* __restrict__ k_out, uint16_t* __restrict__ v_out,
    float* __restrict__ f_out, int N) {
  __shared__ uint16_t lA[128 * 64];
  __shared__ uint16_t lB[128 * 64];
  const int tid = threadIdx.x;
  const int lane = tid & 63;
  const int w = tid >> 6, wm = w >> 1, wn = w & 1;
  const int r16 = lane & 15, hi = lane >> 4;
  const int bn = blockIdx.x, bm = blockIdx.y;

  f32x4 acc[4][4];
#pragma unroll
  for (int i = 0; i < 4; ++i)
#pragma unroll
    for (int j = 0; j < 4; ++j) acc[i][j] = (f32x4){0.f, 0.f, 0.f, 0.f};

  const int ksteps = K >> 6;
  for (int kt = 0; kt < ksteps; ++kt) {
    // stage A,B tiles (128x64 bf16 each) via global_load_lds, source-side XOR swizzle
#pragma unroll
    for (int it = 0; it < 4; ++it) {
      int ci = it * 256 + tid;       // 16B chunk index, 0..1023
      int row = ci >> 3;             // tile row 0..127
      int cch = (ci & 7) ^ (row & 7);// swizzled source column-chunk
      stage16(A + (size_t)(bm * 128 + row) * K + kt * 64 + cch * 8, &lA[ci * 8]);
      stage16(Bt + (size_t)(bn * 128 + row) * K + kt * 64 + cch * 8, &lB[ci * 8]);
    }
    __syncthreads();
#pragma unroll
    for (int kk = 0; kk < 2; ++kk) {
      short8 af[4], bfr[4];
      int swz = (kk * 64 + hi * 16) ^ ((r16 & 7) << 4);  // byte offset within 128B row
#pragma unroll
      for (int i = 0; i < 4; ++i) {
        int rowa = wm * 64 + i * 16 + r16;
        af[i] = *(const short8*)((const char*)lA + rowa * 128 + swz);
        int rowb = wn * 64 + i * 16 + r16;
        bfr[i] = *(const short8*)((const char*)lB + rowb * 128 + swz);
      }
#pragma unroll
      for (int i = 0; i < 4; ++i)
#pragma unroll
        for (int j = 0; j < 4; ++j)
          acc[i][j] = __builtin_amdgcn_mfma_f32_16x16x32_bf16(af[i], bfr[j], acc[i][j], 0, 0, 0);
    }
    __syncthreads();
  }

  // epilogue: D row = (lane>>4)*4 + r, col = lane&15  [verified m89/m91]
#pragma unroll
  for (int i = 0; i < 4; ++i) {
    int rbase = bm * 128 + wm * 64 + i * 16 + hi * 4;
#pragma unroll
    for (int j = 0; j < 4; ++j) {
      int cg = bn * 128 + wn * 64 + j * 16 + r16;
      float bv = bias[cg];
      if (MODE == 0) {
        int which = cg >> 10, hh = (cg >> 6) & 15, dd = cg & 63;
        uint16_t* dst = which == 0 ? q_out : (which == 1 ? k_out : v_out);
#pragma unroll
        for (int r = 0; r < 4; ++r) {
          int rg = rbase + r;
          int bb = rg >> 11, tt = rg & 2047;
          dst[((size_t)(bb * 16 + hh) * 2048 + tt) * 64 + dd] = f2bf(acc[i][j][r] + bv);
        }
      } else {
#pragma unroll
        for (int r = 0; r < 4; ++r) {
          int rg = rbase + r;
          f_out[(size_t)rg * N + cg] = acc[i][j][r] + bv;
        }
      }
    }
  }
}

// ---------------- causal flash attention ----------------
// Q,K: [BH][2048][64] bf16; Vt: [BH][64][2048] bf16; O: [B,T,C] bf16
// block: 4 waves, each wave owns 32 q-rows (2 strips of 16); KV tiles of 32.
__global__ __launch_bounds__(256) void attn_fwd(
    const uint16_t* __restrict__ Qm, const uint16_t* __restrict__ Km,
    const uint16_t* __restrict__ Vt, uint16_t* __restrict__ O) {
  __shared__ uint16_t plds[4][2][16 * 40];  // padded stride 40 to spread banks
  const int tid = threadIdx.x;
  const int lane = tid & 63, w = tid >> 6;
  const int r16 = lane & 15, hi = lane >> 4;
  const int bh = blockIdx.y;
  const int b = bh >> 4, h = bh & 15;
  const size_t base = (size_t)bh * 2048 * 64;
  const int q0w = blockIdx.x * 128 + w * 32;

  // Q fragments held in registers for the whole kernel
  short8 aq[2][2];
#pragma unroll
  for (int s = 0; s < 2; ++s)
#pragma unroll
    for (int c = 0; c < 2; ++c)
      aq[s][c] = *(const short8*)&Qm[base + (size_t)(q0w + s * 16 + r16) * 64 + c * 32 + hi * 8];

  f32x4 o[2][4];
  float m_[2][4], l_[2][4];
#pragma unroll
  for (int s = 0; s < 2; ++s) {
#pragma unroll
    for (int j = 0; j < 4; ++j) o[s][j] = (f32x4){0.f, 0.f, 0.f, 0.f};
#pragma unroll
    for (int r = 0; r < 4; ++r) { m_[s][r] = -1e30f; l_[s][r] = 0.f; }
  }

  const int nt = (q0w >> 5) + 1;
  for (int t = 0; t < nt; ++t) {
    const int kv0 = t << 5;
    // K fragments (shared by both strips)
    short8 bk[2][2];
#pragma unroll
    for (int ct = 0; ct < 2; ++ct)
#pragma unroll
      for (int c = 0; c < 2; ++c)
        bk[ct][c] = *(const short8*)&Km[base + (size_t)(kv0 + ct * 16 + r16) * 64 + c * 32 + hi * 8];
    const bool maskt = (t == nt - 1);

#pragma unroll
    for (int s = 0; s < 2; ++s) {
      f32x4 sc[2];
      sc[0] = (f32x4){0.f, 0.f, 0.f, 0.f};
      sc[1] = (f32x4){0.f, 0.f, 0.f, 0.f};
#pragma unroll
      for (int ct = 0; ct < 2; ++ct)
#pragma unroll
        for (int c = 0; c < 2; ++c)
          sc[ct] = __builtin_amdgcn_mfma_f32_16x16x32_bf16(aq[s][c], bk[ct][c], sc[ct], 0, 0, 0);

      // scale by 0.125*log2(e); causal mask on last tile; S row = q0+hi*4+r, col = kv0+ct*16+r16
      float tv[2][4];
      const int qb_ = q0w + s * 16 + hi * 4;
#pragma unroll
      for (int ct = 0; ct < 2; ++ct)
#pragma unroll
        for (int r = 0; r < 4; ++r) {
          float x = sc[ct][r] * 0.18033688011112042f;
          if (maskt && (kv0 + ct * 16 + r16) > (qb_ + r)) x = -1e30f;
          tv[ct][r] = x;
        }
      float mx[4];
#pragma unroll
      for (int r = 0; r < 4; ++r) mx[r] = fmaxf(tv[0][r], tv[1][r]);
#pragma unroll
      for (int d = 1; d < 16; d <<= 1)
#pragma unroll
        for (int r = 0; r < 4; ++r) mx[r] = fmaxf(mx[r], __shfl_xor(mx[r], d, 64));
      float fac[4];
#pragma unroll
      for (int r = 0; r < 4; ++r) {
        float mn = fmaxf(m_[s][r], mx[r]);
        fac[r] = exp2f(m_[s][r] - mn);
        m_[s][r] = mn;
      }
      float p[2][4];
#pragma unroll
      for (int ct = 0; ct < 2; ++ct)
#pragma unroll
        for (int r = 0; r < 4; ++r) p[ct][r] = exp2f(tv[ct][r] - m_[s][r]);
      float ps[4];
#pragma unroll
      for (int r = 0; r < 4; ++r) ps[r] = p[0][r] + p[1][r];
#pragma unroll
      for (int d = 1; d < 16; d <<= 1)
#pragma unroll
        for (int r = 0; r < 4; ++r) ps[r] += __shfl_xor(ps[r], d, 64);
#pragma unroll
      for (int r = 0; r < 4; ++r) l_[s][r] = l_[s][r] * fac[r] + ps[r];
#pragma unroll
      for (int j = 0; j < 4; ++j)
#pragma unroll
        for (int r = 0; r < 4; ++r) o[s][j][r] *= fac[r];
      // P -> LDS in A-fragment layout (wave-private buffer)
      uint16_t* pl = &plds[w][s][0];
#pragma unroll
      for (int ct = 0; ct < 2; ++ct)
#pragma unroll
        for (int r = 0; r < 4; ++r)
          pl[(hi * 4 + r) * 40 + ct * 16 + r16] = f2bf(p[ct][r]);
    }
    // order LDS write->read (cross-lane within wave); DS pipe is in-order per wave
    asm volatile("s_waitcnt lgkmcnt(0)" ::: "memory");
    __builtin_amdgcn_sched_barrier(0);

    short8 ap[2];
#pragma unroll
    for (int s = 0; s < 2; ++s)
      ap[s] = *(const short8*)&plds[w][s][r16 * 40 + hi * 8];
    short8 bv[4];
#pragma unroll
    for (int j = 0; j < 4; ++j)
      bv[j] = *(const short8*)&Vt[base + (size_t)(j * 16 + r16) * 2048 + kv0 + hi * 8];
#pragma unroll
    for (int s = 0; s < 2; ++s)
#pragma unroll
      for (int j = 0; j < 4; ++j)
        o[s][j] = __builtin_amdgcn_mfma_f32_16x16x32_bf16(ap[s], bv[j], o[s][j], 0, 0, 0);
  }

  // epilogue: O[b][t][h*64+d] bf16
#pragma unroll
  for (int s = 0; s < 2; ++s)
#pragma unroll
    for (int r = 0; r < 4; ++r) {
      float inv = 1.f / l_[s][r];
      int qg = q0w + s * 16 + hi * 4 + r;
      size_t rowo = ((size_t)(b * 2048 + qg)) * 1024 + h * 64;
#pragma unroll
      for (int j = 0; j < 4; ++j)
        O[rowo + j * 16 + r16] = f2bf(o[s][j][r] * inv);
    }
}

// ---------------- launch ----------------

extern "C" void kernel_launch(void* const* d_in, const int* in_sizes, int n_in,
                              void* d_out, int out_size, void* d_ws, size_t ws_size,
                              hipStream_t stream) {
  const float* x = (const float*)d_in[0];
  const float* w_qkv = (const float*)d_in[1];
  const float* b_qkv = (const float*)d_in[2];
  const float* w_out = (const float*)d_in[3];
  const float* b_out = (const float*)d_in[4];
  float* out = (float*)d_out;

  const size_t BT = 8192, C = 1024, N3 = 3072, BHTD = 8388608;
  char* p = (char*)d_ws;
  uint16_t* xbf = (uint16_t*)p;   p += BT * C * 2;
  uint16_t* wqkvT = (uint16_t*)p; p += N3 * C * 2;
  uint16_t* woutT = (uint16_t*)p; p += C * C * 2;
  uint16_t* qb = (uint16_t*)p;    p += BHTD * 2;
  uint16_t* kb = (uint16_t*)p;    p += BHTD * 2;
  uint16_t* vb = (uint16_t*)p;    p += BHTD * 2;
  uint16_t* vtb = (uint16_t*)p;   p += BHTD * 2;
  uint16_t* ob = (uint16_t*)p;    p += BHTD * 2;

  cvt_f32_bf16<<<2048, 256, 0, stream>>>(x, xbf, (int)(BT * C / 4));
  transpose_cvt<<<dim3(96, 32), dim3(32, 8), 0, stream>>>(w_qkv, wqkvT, 1024, 3072);
  transpose_cvt<<<dim3(32, 32), dim3(32, 8), 0, stream>>>(w_out, woutT, 1024, 1024);
  gemm128<0><<<dim3(24, 64), 256, 0, stream>>>(xbf, wqkvT, b_qkv, 1024, qb, kb, vb, nullptr, 3072);
  transpose_v<<<dim3(64, 2, 64), dim3(32, 8), 0, stream>>>(vb, vtb);
  attn_fwd<<<dim3(16, 64), 256, 0, stream>>>(qb, kb, vtb, ob);
  gemm128<1><<<dim3(8, 64), 256, 0, stream>>>(ob, woutT, b_out, 1024, nullptr, nullptr, nullptr, out, 1024);
}

// Round 2
// 264.886 us; speedup vs baseline: 1.6722x; 1.6722x over previous
//
#include <hip/hip_runtime.h>
#include <cstdint>
#include <cstddef>

typedef __attribute__((ext_vector_type(8))) short short8;
typedef __attribute__((ext_vector_type(4))) float f32x4;
typedef __attribute__((ext_vector_type(4))) uint16_t ushort4_t;

__device__ __forceinline__ uint16_t f2bf(float f) {
  union { float f; uint32_t u; } v; v.f = f;
  uint32_t r = v.u + 0x7FFFu + ((v.u >> 16) & 1u);
  return (uint16_t)(r >> 16);
}

// ---------------- conversion kernels ----------------

__global__ __launch_bounds__(256) void cvt_f32_bf16(const float* __restrict__ in,
                                                    uint16_t* __restrict__ out, int n4) {
  int i = blockIdx.x * 256 + threadIdx.x;
  int stride = gridDim.x * 256;
  for (; i < n4; i += stride) {
    float4 v = ((const float4*)in)[i];
    ushort4_t o = { f2bf(v.x), f2bf(v.y), f2bf(v.z), f2bf(v.w) };
    ((ushort4_t*)out)[i] = o;
  }
}

// out[C][R] (bf16) = transpose of in[R][C] (f32)
__global__ __launch_bounds__(256) void transpose_cvt(const float* __restrict__ in,
                                                     uint16_t* __restrict__ out, int R, int C) {
  __shared__ float tile[32][33];
  int c0 = blockIdx.x * 32, r0 = blockIdx.y * 32;
  int tx = threadIdx.x, ty = threadIdx.y;
#pragma unroll
  for (int j = 0; j < 32; j += 8)
    tile[ty + j][tx] = in[(size_t)(r0 + ty + j) * C + c0 + tx];
  __syncthreads();
#pragma unroll
  for (int j = 0; j < 32; j += 8)
    out[(size_t)(c0 + ty + j) * R + r0 + tx] = f2bf(tile[tx][ty + j]);
}

// v [BH][2048][64] bf16 -> vT [BH][64][2048] bf16
__global__ __launch_bounds__(256) void transpose_v(const uint16_t* __restrict__ in,
                                                   uint16_t* __restrict__ out) {
  __shared__ uint16_t tile[32][33];
  int bh = blockIdx.z;
  int t0 = blockIdx.x * 32, d0 = blockIdx.y * 32;
  const uint16_t* ip = in + (size_t)bh * 2048 * 64;
  uint16_t* op = out + (size_t)bh * 64 * 2048;
  int tx = threadIdx.x, ty = threadIdx.y;
#pragma unroll
  for (int j = 0; j < 32; j += 8)
    tile[ty + j][tx] = ip[(size_t)(t0 + ty + j) * 64 + d0 + tx];
  __syncthreads();
#pragma unroll
  for (int j = 0; j < 32; j += 8)
    op[(size_t)(d0 + ty + j) * 2048 + t0 + tx] = tile[tx][ty + j];
}

// ---------------- GEMM (128x128 tile, BK=64, 4 waves) ----------------

__device__ __forceinline__ void stage16(const uint16_t* g, uint16_t* lds) {
  __builtin_amdgcn_global_load_lds((__attribute__((address_space(1))) void*)g,
                                   (__attribute__((address_space(3))) void*)lds, 16, 0, 0);
}

// C[M][N] = A[M][K] * Bt[N][K]^T + bias
// MODE 0: scatter bf16 into q/k/v [B,H,T,D]; MODE 1: plain f32 row-major out
template <int MODE>
__global__ __launch_bounds__(256) void gemm128(
    const uint16_t* __restrict__ A, const uint16_t* __restrict__ Bt,
    const float* __restrict__ bias, int K,
    uint16_t* __restrict__ q_out, uint16_t* __restrict__ k_out, uint16_t* __restrict__ v_out,
    float* __restrict__ f_out, int N) {
  __shared__ uint16_t lA[128 * 64];
  __shared__ uint16_t lB[128 * 64];
  const int tid = threadIdx.x;
  const int lane = tid & 63;
  const int w = tid >> 6, wm = w >> 1, wn = w & 1;
  const int r16 = lane & 15, hi = lane >> 4;
  const int bn = blockIdx.x, bm = blockIdx.y;

  f32x4 acc[4][4];
#pragma unroll
  for (int i = 0; i < 4; ++i)
#pragma unroll
    for (int j = 0; j < 4; ++j) acc[i][j] = (f32x4){0.f, 0.f, 0.f, 0.f};

  const int ksteps = K >> 6;
  for (int kt = 0; kt < ksteps; ++kt) {
    // stage A,B tiles (128x64 bf16 each) via global_load_lds, source-side XOR swizzle
#pragma unroll
    for (int it = 0; it < 4; ++it) {
      int ci = it * 256 + tid;       // 16B chunk index, 0..1023
      int row = ci >> 3;             // tile row 0..127
      int cch = (ci & 7) ^ (row & 7);// swizzled source column-chunk
      stage16(A + (size_t)(bm * 128 + row) * K + kt * 64 + cch * 8, &lA[ci * 8]);
      stage16(Bt + (size_t)(bn * 128 + row) * K + kt * 64 + cch * 8, &lB[ci * 8]);
    }
    __syncthreads();
#pragma unroll
    for (int kk = 0; kk < 2; ++kk) {
      short8 af[4], bfr[4];
      int swz = (kk * 64 + hi * 16) ^ ((r16 & 7) << 4);  // byte offset within 128B row
#pragma unroll
      for (int i = 0; i < 4; ++i) {
        int rowa = wm * 64 + i * 16 + r16;
        af[i] = *(const short8*)((const char*)lA + rowa * 128 + swz);
        int rowb = wn * 64 + i * 16 + r16;
        bfr[i] = *(const short8*)((const char*)lB + rowb * 128 + swz);
      }
#pragma unroll
      for (int i = 0; i < 4; ++i)
#pragma unroll
        for (int j = 0; j < 4; ++j)
          acc[i][j] = __builtin_amdgcn_mfma_f32_16x16x32_bf16(af[i], bfr[j], acc[i][j], 0, 0, 0);
    }
    __syncthreads();
  }

  // epilogue: D row = (lane>>4)*4 + r, col = lane&15  [verified m89/m91]
#pragma unroll
  for (int i = 0; i < 4; ++i) {
    int rbase = bm * 128 + wm * 64 + i * 16 + hi * 4;
#pragma unroll
    for (int j = 0; j < 4; ++j) {
      int cg = bn * 128 + wn * 64 + j * 16 + r16;
      float bv = bias[cg];
      if (MODE == 0) {
        int which = cg >> 10, hh = (cg >> 6) & 15, dd = cg & 63;
        uint16_t* dst = which == 0 ? q_out : (which == 1 ? k_out : v_out);
#pragma unroll
        for (int r = 0; r < 4; ++r) {
          int rg = rbase + r;
          int bb = rg >> 11, tt = rg & 2047;
          dst[((size_t)(bb * 16 + hh) * 2048 + tt) * 64 + dd] = f2bf(acc[i][j][r] + bv);
        }
      } else {
#pragma unroll
        for (int r = 0; r < 4; ++r) {
          int rg = rbase + r;
          f_out[(size_t)rg * N + cg] = acc[i][j][r] + bv;
        }
      }
    }
  }
}

// ---------------- causal flash attention ----------------
// Q,K: [BH][2048][64] bf16; Vt: [BH][64][2048] bf16; O: [B,T,C] bf16
// 1 wave (64 thr) per block; wave owns one 32-row q-strip; KV tiles of 64.
// grid: x = bh (64), y = strip, dispatched longest-first (s = 63 - y).
__global__ __launch_bounds__(64, 3) void attn_fwd(
    const uint16_t* __restrict__ Qm, const uint16_t* __restrict__ Km,
    const uint16_t* __restrict__ Vt, uint16_t* __restrict__ O) {
  __shared__ uint16_t plds[2][16 * 72];  // P rows padded to 72 elem (144B, 16B-mult)
  const int lane = threadIdx.x;
  const int r16 = lane & 15, hi = lane >> 4;
  const int bh = blockIdx.x;
  const int b = bh >> 4, h = bh & 15;
  const int s = 63 - blockIdx.y;       // strip id; long strips dispatch first
  const size_t base = (size_t)bh * 2048 * 64;
  const int q0 = s * 32;
  const int nt = (s >> 1) + 1;         // KVBLK=64 tiles covering [0, 32s+32)

  // Q fragments held in registers for the whole kernel
  short8 aq[2][2];
#pragma unroll
  for (int st = 0; st < 2; ++st)
#pragma unroll
    for (int c = 0; c < 2; ++c)
      aq[st][c] = *(const short8*)&Qm[base + (size_t)(q0 + st * 16 + r16) * 64 + c * 32 + hi * 8];

  f32x4 o[2][4];
  float m_[2][4], l_[2][4];
#pragma unroll
  for (int st = 0; st < 2; ++st) {
#pragma unroll
    for (int j = 0; j < 4; ++j) o[st][j] = (f32x4){0.f, 0.f, 0.f, 0.f};
#pragma unroll
    for (int r = 0; r < 4; ++r) { m_[st][r] = -1e30f; l_[st][r] = 0.f; }
  }

  for (int t = 0; t < nt; ++t) {
    const int kv0 = t << 6;
    // K fragments for 64 kv rows
    short8 bk[4][2];
#pragma unroll
    for (int ct = 0; ct < 4; ++ct)
#pragma unroll
      for (int c = 0; c < 2; ++c)
        bk[ct][c] = *(const short8*)&Km[base + (size_t)(kv0 + ct * 16 + r16) * 64 + c * 32 + hi * 8];
    const bool maskt = (t == nt - 1);

#pragma unroll
    for (int st = 0; st < 2; ++st) {
      f32x4 sc[4];
#pragma unroll
      for (int ct = 0; ct < 4; ++ct) sc[ct] = (f32x4){0.f, 0.f, 0.f, 0.f};
#pragma unroll
      for (int ct = 0; ct < 4; ++ct)
#pragma unroll
        for (int c = 0; c < 2; ++c)
          sc[ct] = __builtin_amdgcn_mfma_f32_16x16x32_bf16(aq[st][c], bk[ct][c], sc[ct], 0, 0, 0);

      // scale by 0.125*log2(e); causal mask only on last tile
      float tv[4][4];
      const int qb_ = q0 + st * 16 + hi * 4;
#pragma unroll
      for (int ct = 0; ct < 4; ++ct)
#pragma unroll
        for (int r = 0; r < 4; ++r) {
          float x = sc[ct][r] * 0.18033688011112042f;
          if (maskt && (kv0 + ct * 16 + r16) > (qb_ + r)) x = -1e30f;
          tv[ct][r] = x;
        }
      float mx[4];
#pragma unroll
      for (int r = 0; r < 4; ++r)
        mx[r] = fmaxf(fmaxf(tv[0][r], tv[1][r]), fmaxf(tv[2][r], tv[3][r]));
#pragma unroll
      for (int d = 1; d < 16; d <<= 1)
#pragma unroll
        for (int r = 0; r < 4; ++r) mx[r] = fmaxf(mx[r], __shfl_xor(mx[r], d, 64));
      float fac[4];
#pragma unroll
      for (int r = 0; r < 4; ++r) {
        float mn = fmaxf(m_[st][r], mx[r]);
        fac[r] = exp2f(m_[st][r] - mn);
        m_[st][r] = mn;
      }
      float p[4][4];
#pragma unroll
      for (int ct = 0; ct < 4; ++ct)
#pragma unroll
        for (int r = 0; r < 4; ++r) p[ct][r] = exp2f(tv[ct][r] - m_[st][r]);
      float ps[4];
#pragma unroll
      for (int r = 0; r < 4; ++r) ps[r] = (p[0][r] + p[1][r]) + (p[2][r] + p[3][r]);
#pragma unroll
      for (int d = 1; d < 16; d <<= 1)
#pragma unroll
        for (int r = 0; r < 4; ++r) ps[r] += __shfl_xor(ps[r], d, 64);
#pragma unroll
      for (int r = 0; r < 4; ++r) l_[st][r] = l_[st][r] * fac[r] + ps[r];
#pragma unroll
      for (int j = 0; j < 4; ++j)
#pragma unroll
        for (int r = 0; r < 4; ++r) o[st][j][r] *= fac[r];
      // P -> LDS in A-fragment layout
      uint16_t* pl = &plds[st][0];
#pragma unroll
      for (int ct = 0; ct < 4; ++ct)
#pragma unroll
        for (int r = 0; r < 4; ++r)
          pl[(hi * 4 + r) * 72 + ct * 16 + r16] = f2bf(p[ct][r]);
    }
    // order LDS writes before reads (same wave, DS pipe)
    asm volatile("s_waitcnt lgkmcnt(0)" ::: "memory");
    __builtin_amdgcn_sched_barrier(0);

    short8 ap[2][2];
#pragma unroll
    for (int st = 0; st < 2; ++st)
#pragma unroll
      for (int ks = 0; ks < 2; ++ks)
        ap[st][ks] = *(const short8*)&plds[st][r16 * 72 + ks * 32 + hi * 8];
    short8 bv[4][2];
#pragma unroll
    for (int j = 0; j < 4; ++j)
#pragma unroll
      for (int ks = 0; ks < 2; ++ks)
        bv[j][ks] = *(const short8*)&Vt[base + (size_t)(j * 16 + r16) * 2048 + kv0 + ks * 32 + hi * 8];
#pragma unroll
    for (int st = 0; st < 2; ++st)
#pragma unroll
      for (int j = 0; j < 4; ++j)
#pragma unroll
        for (int ks = 0; ks < 2; ++ks)
          o[st][j] = __builtin_amdgcn_mfma_f32_16x16x32_bf16(ap[st][ks], bv[j][ks], o[st][j], 0, 0, 0);
  }

  // epilogue: O[b][t][h*64+d] bf16
#pragma unroll
  for (int st = 0; st < 2; ++st)
#pragma unroll
    for (int r = 0; r < 4; ++r) {
      float inv = 1.f / l_[st][r];
      int qg = q0 + st * 16 + hi * 4 + r;
      size_t rowo = ((size_t)(b * 2048 + qg)) * 1024 + h * 64;
#pragma unroll
      for (int j = 0; j < 4; ++j)
        O[rowo + j * 16 + r16] = f2bf(o[st][j][r] * inv);
    }
}

// ---------------- launch ----------------

extern "C" void kernel_launch(void* const* d_in, const int* in_sizes, int n_in,
                              void* d_out, int out_size, void* d_ws, size_t ws_size,
                              hipStream_t stream) {
  const float* x = (const float*)d_in[0];
  const float* w_qkv = (const float*)d_in[1];
  const float* b_qkv = (const float*)d_in[2];
  const float* w_out = (const float*)d_in[3];
  const float* b_out = (const float*)d_in[4];
  float* out = (float*)d_out;

  const size_t BT = 8192, C = 1024, N3 = 3072, BHTD = 8388608;
  char* p = (char*)d_ws;
  uint16_t* xbf = (uint16_t*)p;   p += BT * C * 2;
  uint16_t* wqkvT = (uint16_t*)p; p += N3 * C * 2;
  uint16_t* woutT = (uint16_t*)p; p += C * C * 2;
  uint16_t* qb = (uint16_t*)p;    p += BHTD * 2;
  uint16_t* kb = (uint16_t*)p;    p += BHTD * 2;
  uint16_t* vb = (uint16_t*)p;    p += BHTD * 2;
  uint16_t* vtb = (uint16_t*)p;   p += BHTD * 2;
  uint16_t* ob = (uint16_t*)p;    p += BHTD * 2;

  cvt_f32_bf16<<<2048, 256, 0, stream>>>(x, xbf, (int)(BT * C / 4));
  transpose_cvt<<<dim3(96, 32), dim3(32, 8), 0, stream>>>(w_qkv, wqkvT, 1024, 3072);
  transpose_cvt<<<dim3(32, 32), dim3(32, 8), 0, stream>>>(w_out, woutT, 1024, 1024);
  gemm128<0><<<dim3(24, 64), 256, 0, stream>>>(xbf, wqkvT, b_qkv, 1024, qb, kb, vb, nullptr, 3072);
  transpose_v<<<dim3(64, 2, 64), dim3(32, 8), 0, stream>>>(vb, vtb);
  attn_fwd<<<dim3(64, 64), 64, 0, stream>>>(qb, kb, vtb, ob);
  gemm128<1><<<dim3(8, 64), 256, 0, stream>>>(ob, woutT, b_out, 1024, nullptr, nullptr, nullptr, out, 1024);
}

// Round 3
// 246.304 us; speedup vs baseline: 1.7984x; 1.0754x over previous
//
#include <hip/hip_runtime.h>
#include <hip/hip_bf16.h>
#include <cstdint>
#include <cstddef>

typedef __attribute__((ext_vector_type(8))) short short8;
typedef __attribute__((ext_vector_type(4))) float f32x4;
typedef __attribute__((ext_vector_type(4))) uint16_t ushort4_t;

__device__ __forceinline__ uint16_t f2bf(float f) {
  union { float f; uint32_t u; } v; v.f = f;
  uint32_t r = v.u + 0x7FFFu + ((v.u >> 16) & 1u);
  return (uint16_t)(r >> 16);
}

__device__ __forceinline__ uint16_t f2bf_hw(float f) {
  union { __hip_bfloat16 h; uint16_t u; } cv;
  cv.h = __float2bfloat16(f);
  return cv.u;
}

// ---------------- conversion kernels ----------------

__global__ __launch_bounds__(256) void cvt_f32_bf16(const float* __restrict__ in,
                                                    uint16_t* __restrict__ out, int n4) {
  int i = blockIdx.x * 256 + threadIdx.x;
  int stride = gridDim.x * 256;
  for (; i < n4; i += stride) {
    float4 v = ((const float4*)in)[i];
    ushort4_t o = { f2bf(v.x), f2bf(v.y), f2bf(v.z), f2bf(v.w) };
    ((ushort4_t*)out)[i] = o;
  }
}

// out[C][R] (bf16) = transpose of in[R][C] (f32)
__global__ __launch_bounds__(256) void transpose_cvt(const float* __restrict__ in,
                                                     uint16_t* __restrict__ out, int R, int C) {
  __shared__ float tile[32][33];
  int c0 = blockIdx.x * 32, r0 = blockIdx.y * 32;
  int tx = threadIdx.x, ty = threadIdx.y;
#pragma unroll
  for (int j = 0; j < 32; j += 8)
    tile[ty + j][tx] = in[(size_t)(r0 + ty + j) * C + c0 + tx];
  __syncthreads();
#pragma unroll
  for (int j = 0; j < 32; j += 8)
    out[(size_t)(c0 + ty + j) * R + r0 + tx] = f2bf(tile[tx][ty + j]);
}

// v [BH][2048][64] bf16 -> vT [BH][64][2048] bf16
__global__ __launch_bounds__(256) void transpose_v(const uint16_t* __restrict__ in,
                                                   uint16_t* __restrict__ out) {
  __shared__ uint16_t tile[32][33];
  int bh = blockIdx.z;
  int t0 = blockIdx.x * 32, d0 = blockIdx.y * 32;
  const uint16_t* ip = in + (size_t)bh * 2048 * 64;
  uint16_t* op = out + (size_t)bh * 64 * 2048;
  int tx = threadIdx.x, ty = threadIdx.y;
#pragma unroll
  for (int j = 0; j < 32; j += 8)
    tile[ty + j][tx] = ip[(size_t)(t0 + ty + j) * 64 + d0 + tx];
  __syncthreads();
#pragma unroll
  for (int j = 0; j < 32; j += 8)
    op[(size_t)(d0 + ty + j) * 2048 + t0 + tx] = tile[tx][ty + j];
}

// ---------------- GEMM (128x128 tile, BK=64, 4 waves) ----------------

__device__ __forceinline__ void stage16(const uint16_t* g, uint16_t* lds) {
  __builtin_amdgcn_global_load_lds((__attribute__((address_space(1))) void*)g,
                                   (__attribute__((address_space(3))) void*)lds, 16, 0, 0);
}

// C[M][N] = A[M][K] * Bt[N][K]^T + bias
// MODE 0: scatter bf16 into q/k/v [B,H,T,D]; MODE 1: plain f32 row-major out
template <int MODE>
__global__ __launch_bounds__(256) void gemm128(
    const uint16_t* __restrict__ A, const uint16_t* __restrict__ Bt,
    const float* __restrict__ bias, int K,
    uint16_t* __restrict__ q_out, uint16_t* __restrict__ k_out, uint16_t* __restrict__ v_out,
    float* __restrict__ f_out, int N) {
  __shared__ uint16_t lA[128 * 64];
  __shared__ uint16_t lB[128 * 64];
  const int tid = threadIdx.x;
  const int lane = tid & 63;
  const int w = tid >> 6, wm = w >> 1, wn = w & 1;
  const int r16 = lane & 15, hi = lane >> 4;
  const int bn = blockIdx.x, bm = blockIdx.y;

  f32x4 acc[4][4];
#pragma unroll
  for (int i = 0; i < 4; ++i)
#pragma unroll
    for (int j = 0; j < 4; ++j) acc[i][j] = (f32x4){0.f, 0.f, 0.f, 0.f};

  const int ksteps = K >> 6;
  for (int kt = 0; kt < ksteps; ++kt) {
    // stage A,B tiles (128x64 bf16 each) via global_load_lds, source-side XOR swizzle
#pragma unroll
    for (int it = 0; it < 4; ++it) {
      int ci = it * 256 + tid;       // 16B chunk index, 0..1023
      int row = ci >> 3;             // tile row 0..127
      int cch = (ci & 7) ^ (row & 7);// swizzled source column-chunk
      stage16(A + (size_t)(bm * 128 + row) * K + kt * 64 + cch * 8, &lA[ci * 8]);
      stage16(Bt + (size_t)(bn * 128 + row) * K + kt * 64 + cch * 8, &lB[ci * 8]);
    }
    __syncthreads();
#pragma unroll
    for (int kk = 0; kk < 2; ++kk) {
      short8 af[4], bfr[4];
      int swz = (kk * 64 + hi * 16) ^ ((r16 & 7) << 4);  // byte offset within 128B row
#pragma unroll
      for (int i = 0; i < 4; ++i) {
        int rowa = wm * 64 + i * 16 + r16;
        af[i] = *(const short8*)((const char*)lA + rowa * 128 + swz);
        int rowb = wn * 64 + i * 16 + r16;
        bfr[i] = *(const short8*)((const char*)lB + rowb * 128 + swz);
      }
#pragma unroll
      for (int i = 0; i < 4; ++i)
#pragma unroll
        for (int j = 0; j < 4; ++j)
          acc[i][j] = __builtin_amdgcn_mfma_f32_16x16x32_bf16(af[i], bfr[j], acc[i][j], 0, 0, 0);
    }
    __syncthreads();
  }

  // epilogue: D row = (lane>>4)*4 + r, col = lane&15  [verified m89/m91]
#pragma unroll
  for (int i = 0; i < 4; ++i) {
    int rbase = bm * 128 + wm * 64 + i * 16 + hi * 4;
#pragma unroll
    for (int j = 0; j < 4; ++j) {
      int cg = bn * 128 + wn * 64 + j * 16 + r16;
      float bv = bias[cg];
      if (MODE == 0) {
        int which = cg >> 10, hh = (cg >> 6) & 15, dd = cg & 63;
        uint16_t* dst = which == 0 ? q_out : (which == 1 ? k_out : v_out);
#pragma unroll
        for (int r = 0; r < 4; ++r) {
          int rg = rbase + r;
          int bb = rg >> 11, tt = rg & 2047;
          dst[((size_t)(bb * 16 + hh) * 2048 + tt) * 64 + dd] = f2bf(acc[i][j][r] + bv);
        }
      } else {
#pragma unroll
        for (int r = 0; r < 4; ++r) {
          int rg = rbase + r;
          f_out[(size_t)rg * N + cg] = acc[i][j][r] + bv;
        }
      }
    }
  }
}

// ---------------- causal flash attention ----------------
// Q,K: [BH][2048][64] bf16; Vt: [BH][64][2048] bf16; O: [B,T,C] bf16
// 1 wave per block, one 32-row q-strip per wave, KV tiles of 64.
// Fixed-max softmax (M=14): p = exp2(s*0.1803 - 20.198) -- exact math, no
// online rescale. Row-sum l computed by an extra ones-A-fragment MFMA.
// PV uses swapped operands (A=V-frag, B=P-frag) so output is O^T
// (col=q, row=d): l is lane-local for the epilogue and stores vectorize.
__global__ __launch_bounds__(64, 3) void attn_fwd(
    const uint16_t* __restrict__ Qm, const uint16_t* __restrict__ Km,
    const uint16_t* __restrict__ Vt, uint16_t* __restrict__ O) {
  __shared__ uint16_t plds[2][16 * 72];  // P rows padded to 72 elem (144B)
  const int lane = threadIdx.x;
  const int r16 = lane & 15, hi = lane >> 4;
  const int bh = blockIdx.x;
  const int b = bh >> 4, h = bh & 15;
  const int s = 63 - blockIdx.y;       // strip id; long strips dispatch first
  const size_t base = (size_t)bh * 2048 * 64;
  const int q0 = s * 32;
  const int nfull = s >> 1;            // unmasked KV-64 tiles; 1 masked tile after

  const float SC = 0.18033688011112042f;   // 0.125 * log2(e)
  const float BIAS = -20.197730572445487f; // -14 * log2(e)

  short8 aq[2][2];
#pragma unroll
  for (int st = 0; st < 2; ++st)
#pragma unroll
    for (int c = 0; c < 2; ++c)
      aq[st][c] = *(const short8*)&Qm[base + (size_t)(q0 + st * 16 + r16) * 64 + c * 32 + hi * 8];

  f32x4 o[2][4];   // O^T fragments: col=q (r16), row=d (j*16+hi*4+r)
  f32x4 o4[2];     // l accumulator (every reg = l[q=r16])
#pragma unroll
  for (int st = 0; st < 2; ++st) {
#pragma unroll
    for (int j = 0; j < 4; ++j) o[st][j] = (f32x4){0.f, 0.f, 0.f, 0.f};
    o4[st] = (f32x4){0.f, 0.f, 0.f, 0.f};
  }
  short8 ones8;
#pragma unroll
  for (int i = 0; i < 8; ++i) ones8[i] = (short)0x3F80;  // bf16 1.0

  auto tile = [&](int kv0, bool maskt) {
    short8 bk[4][2];
#pragma unroll
    for (int ct = 0; ct < 4; ++ct)
#pragma unroll
      for (int c = 0; c < 2; ++c)
        bk[ct][c] = *(const short8*)&Km[base + (size_t)(kv0 + ct * 16 + r16) * 64 + c * 32 + hi * 8];

#pragma unroll
    for (int st = 0; st < 2; ++st) {
      f32x4 sc[4];
#pragma unroll
      for (int ct = 0; ct < 4; ++ct) sc[ct] = (f32x4){0.f, 0.f, 0.f, 0.f};
#pragma unroll
      for (int ct = 0; ct < 4; ++ct)
#pragma unroll
        for (int c = 0; c < 2; ++c)
          sc[ct] = __builtin_amdgcn_mfma_f32_16x16x32_bf16(aq[st][c], bk[ct][c], sc[ct], 0, 0, 0);

      uint16_t* pl = &plds[st][0];
      const int rowq = q0 + st * 16 + hi * 4;
#pragma unroll
      for (int ct = 0; ct < 4; ++ct)
#pragma unroll
        for (int r = 0; r < 4; ++r) {
          float p = exp2f(fmaf(sc[ct][r], SC, BIAS));
          if (maskt && (kv0 + ct * 16 + r16) > (rowq + r)) p = 0.f;
          pl[(hi * 4 + r) * 72 + ct * 16 + r16] = f2bf_hw(p);
        }
    }
    // order LDS writes before reads (single wave, DS pipe)
    asm volatile("s_waitcnt lgkmcnt(0)" ::: "memory");
    __builtin_amdgcn_sched_barrier(0);

    short8 ap[2][2];
#pragma unroll
    for (int st = 0; st < 2; ++st)
#pragma unroll
      for (int ks = 0; ks < 2; ++ks)
        ap[st][ks] = *(const short8*)&plds[st][r16 * 72 + ks * 32 + hi * 8];
    short8 bv[4][2];
#pragma unroll
    for (int j = 0; j < 4; ++j)
#pragma unroll
      for (int ks = 0; ks < 2; ++ks)
        bv[j][ks] = *(const short8*)&Vt[base + (size_t)(j * 16 + r16) * 2048 + kv0 + ks * 32 + hi * 8];
#pragma unroll
    for (int st = 0; st < 2; ++st) {
#pragma unroll
      for (int ks = 0; ks < 2; ++ks)
        o4[st] = __builtin_amdgcn_mfma_f32_16x16x32_bf16(ones8, ap[st][ks], o4[st], 0, 0, 0);
#pragma unroll
      for (int j = 0; j < 4; ++j)
#pragma unroll
        for (int ks = 0; ks < 2; ++ks)
          o[st][j] = __builtin_amdgcn_mfma_f32_16x16x32_bf16(bv[j][ks], ap[st][ks], o[st][j], 0, 0, 0);
    }
  };

  for (int t = 0; t < nfull; ++t) tile(t << 6, false);
  tile(nfull << 6, true);

  // epilogue: O^T layout -> O[b][q][h*64 + d], 8B vector stores
#pragma unroll
  for (int st = 0; st < 2; ++st) {
    float inv = 1.f / o4[st][0];
    int qg = q0 + st * 16 + r16;
    size_t rowo = ((size_t)(b * 2048 + qg)) * 1024 + h * 64;
#pragma unroll
    for (int j = 0; j < 4; ++j) {
      ushort4_t v4 = { f2bf(o[st][j][0] * inv), f2bf(o[st][j][1] * inv),
                       f2bf(o[st][j][2] * inv), f2bf(o[st][j][3] * inv) };
      *(ushort4_t*)&O[rowo + j * 16 + hi * 4] = v4;
    }
  }
}

// ---------------- launch ----------------

extern "C" void kernel_launch(void* const* d_in, const int* in_sizes, int n_in,
                              void* d_out, int out_size, void* d_ws, size_t ws_size,
                              hipStream_t stream) {
  const float* x = (const float*)d_in[0];
  const float* w_qkv = (const float*)d_in[1];
  const float* b_qkv = (const float*)d_in[2];
  const float* w_out = (const float*)d_in[3];
  const float* b_out = (const float*)d_in[4];
  float* out = (float*)d_out;

  const size_t BT = 8192, C = 1024, N3 = 3072, BHTD = 8388608;
  char* p = (char*)d_ws;
  uint16_t* xbf = (uint16_t*)p;   p += BT * C * 2;
  uint16_t* wqkvT = (uint16_t*)p; p += N3 * C * 2;
  uint16_t* woutT = (uint16_t*)p; p += C * C * 2;
  uint16_t* qb = (uint16_t*)p;    p += BHTD * 2;
  uint16_t* kb = (uint16_t*)p;    p += BHTD * 2;
  uint16_t* vb = (uint16_t*)p;    p += BHTD * 2;
  uint16_t* vtb = (uint16_t*)p;   p += BHTD * 2;
  uint16_t* ob = (uint16_t*)p;    p += BHTD * 2;

  cvt_f32_bf16<<<2048, 256, 0, stream>>>(x, xbf, (int)(BT * C / 4));
  transpose_cvt<<<dim3(96, 32), dim3(32, 8), 0, stream>>>(w_qkv, wqkvT, 1024, 3072);
  transpose_cvt<<<dim3(32, 32), dim3(32, 8), 0, stream>>>(w_out, woutT, 1024, 1024);
  gemm128<0><<<dim3(24, 64), 256, 0, stream>>>(xbf, wqkvT, b_qkv, 1024, qb, kb, vb, nullptr, 3072);
  transpose_v<<<dim3(64, 2, 64), dim3(32, 8), 0, stream>>>(vb, vtb);
  attn_fwd<<<dim3(64, 64), 64, 0, stream>>>(qb, kb, vtb, ob);
  gemm128<1><<<dim3(8, 64), 256, 0, stream>>>(ob, woutT, b_out, 1024, nullptr, nullptr, nullptr, out, 1024);
}